// Round 4
// baseline (179.725 us; speedup 1.0000x reference)
//
#include <hip/hip_runtime.h>
#include <math.h>

constexpr int N   = 4096;   // nodes
constexpr int F   = 256;    // IN_FEAT (= NH*HID)
constexpr int NH  = 8;      // heads
constexpr int HID = 32;     // hidden per head
constexpr float SLOPE = 0.2f;

using h2       = __attribute__((ext_vector_type(2))) _Float16;
using frag_f16 = __attribute__((ext_vector_type(8))) _Float16;  // 4 VGPRs
using frag_cd  = __attribute__((ext_vector_type(4))) float;
using frag_c16 = __attribute__((ext_vector_type(16))) float;

__device__ inline unsigned short f2h(float x) {
  _Float16 v = (_Float16)x;
  unsigned short u; __builtin_memcpy(&u, &v, 2); return u;
}

// ================= K_U: U[c][k] = sum_f W[head*32+f][k] * a[side*32+f] =================
__global__ __launch_bounds__(256) void k_u(const float* __restrict__ W,
                                           const float* __restrict__ a,
                                           float* __restrict__ U) {
  const int c = blockIdx.x, k = threadIdx.x;
  const int head = c & 7, side = c >> 3;
  float acc = 0.f;
#pragma unroll
  for (int f = 0; f < 32; ++f)
    acc += W[(size_t)(head * 32 + f) * F + k] * a[side * 32 + f];
  U[c * F + k] = acc;
}

// ================= K_SLN: s = h@U (U from global, L1-hot) -> RT2, BT, DT ==========
__global__ __launch_bounds__(256) void k_sln(const float* __restrict__ h,
                                             const float* __restrict__ U,
                                             unsigned int* __restrict__ RT2,
                                             unsigned short* __restrict__ BT,
                                             unsigned short* __restrict__ DT) {
  const int b = blockIdx.x, t = threadIdx.x;
  const int i0 = b * 16;
  const int r = t >> 4, c = t & 15;
  const float4* hp = (const float4*)(h + (size_t)(i0 + r) * F);
  const float4* up = (const float4*)(U + (size_t)c * F);
  float acc = 0.f;
#pragma unroll
  for (int k4 = 0; k4 < 64; ++k4) {
    const float4 hv = hp[k4];
    const float4 uv = up[k4];
    acc += hv.x * uv.x + hv.y * uv.y + hv.z * uv.z + hv.w * uv.w;
  }
  const int n = i0 + r;
  if (c < 8) {
    const unsigned int r16 = f2h(__expf(-0.8f * acc));
    RT2[(size_t)n * NH + c] = (r16 << 16) | r16;
  } else {
    const int hd = c - 8;
    BT[(size_t)hd * N + n] = f2h(__expf(acc));
    DT[(size_t)hd * N + n] = f2h(__expf(SLOPE * acc));
  }
}

// ================= K_GEMM: gT = (h @ W^T)^T fp16 via MFMA ==========
__global__ __launch_bounds__(256) void k_gemm(const float* __restrict__ h,
                                              const float* __restrict__ W,
                                              unsigned short* __restrict__ gT) {
  const int b = blockIdx.x, t = threadIdx.x;
  const int lane = t & 63;
  const int tile = b * 4 + (t >> 6);
  const int mt = tile >> 4, nt = tile & 15;
  const int m0 = mt * 16, n0 = nt * 16;
  const int n16 = lane & 15, quad = lane >> 4;
  frag_cd acc = {0.f, 0.f, 0.f, 0.f};
  const float* ap = h + (size_t)(m0 + n16) * F + quad * 8;
  const float* bp = W + (size_t)(n0 + n16) * F + quad * 8;
#pragma unroll
  for (int ks = 0; ks < F / 32; ++ks) {
    const float4 a0 = *(const float4*)(ap + ks * 32);
    const float4 a1 = *(const float4*)(ap + ks * 32 + 4);
    const float4 b0 = *(const float4*)(bp + ks * 32);
    const float4 b1 = *(const float4*)(bp + ks * 32 + 4);
    const frag_f16 af = {(_Float16)a0.x, (_Float16)a0.y, (_Float16)a0.z, (_Float16)a0.w,
                         (_Float16)a1.x, (_Float16)a1.y, (_Float16)a1.z, (_Float16)a1.w};
    const frag_f16 bf = {(_Float16)b0.x, (_Float16)b0.y, (_Float16)b0.z, (_Float16)b0.w,
                         (_Float16)b1.x, (_Float16)b1.y, (_Float16)b1.z, (_Float16)b1.w};
    acc = __builtin_amdgcn_mfma_f32_16x16x32_f16(af, bf, acc, 0, 0, 0);
  }
  unsigned short tmp[4];
#pragma unroll
  for (int reg = 0; reg < 4; ++reg) tmp[reg] = f2h(acc[reg]);
  *(int2*)(gT + (size_t)(n0 + n16) * N + m0 + quad * 4) = *(int2*)tmp;
}

// ================= K_BITS: adjacency bitmask, wave-contiguous + shfl_xor ==========
__global__ __launch_bounds__(256) void k_bits(const int* __restrict__ adj,
                                              unsigned int* __restrict__ bits) {
  const int b = blockIdx.x, t = threadIdx.x;
  const int lane = t & 63;
  const int wv   = t >> 6;
  const int row  = b * 2 + (wv >> 1);
  const int half = wv & 1;  // each wave covers 2048 ints = 8 KB
  const int4* src4 = (const int4*)(adj + (size_t)row * N) + half * 512 + lane;
  const int shamt = (lane & 7) * 4;
  unsigned int* dstw = bits + (size_t)row * (N / 32) + half * 64 + (lane >> 3);
#pragma unroll
  for (int it = 0; it < 8; ++it) {
    const int4 v4 = src4[it * 64];
    unsigned int v = ((unsigned)v4.x | ((unsigned)v4.y << 1) |
                      ((unsigned)v4.z << 2) | ((unsigned)v4.w << 3)) << shamt;
    v |= (unsigned)__shfl_xor((int)v, 1);
    v |= (unsigned)__shfl_xor((int)v, 2);
    v |= (unsigned)__shfl_xor((int)v, 4);
    if ((lane & 7) == 0) dstw[it * 8] = v;
  }
}

// ================= K_AGG: 64i-tile 32x32 fp16-MFMA flash aggregation =================
// block = 64 i x head-pair x 1/4 j (1024 j); waves: (hd = wv>>1, isub = wv&1).
// sB: stride-128 + XOR-granule swizzle (granule = 8 shorts = 16 B):
//   physical_granule = logical_granule ^ (row & 15)
// -> every fragment read is ONE aligned ds_read_b128 with even bank coverage;
//    every staging write is ONE ds_write_b128. B/D slab broadcast from LDS.
constexpr int TI = 64;
constexpr int NSPLIT = 4;

__global__ __launch_bounds__(256, 4) void k_agg(
    const unsigned short* __restrict__ gT,
    const unsigned int* __restrict__ RT2,
    const unsigned short* __restrict__ BT, const unsigned short* __restrict__ DT,
    const unsigned int* __restrict__ bits,
    float* __restrict__ parts, float* __restrict__ lparts) {
  __shared__ __align__(16) unsigned short sB[64][128];   // gT chunk, swizzled granules
  __shared__ __align__(16) uint4 sBD[2][2][128];         // [B/D][head][1024 fp16]

  const int t    = threadIdx.x;
  const int lane = t & 63;
  const int wv   = t >> 6;
  const int isub = wv & 1;
  const int hd   = wv >> 1;
  const int b    = blockIdx.x;
  const int hp   = b & 3;
  const int js   = (b >> 2) & (NSPLIT - 1);
  const int i0   = (b >> 4) * TI;
  const int head = hp * 2 + hd;

  const int n32 = lane & 31;
  const int kh  = lane >> 5;

  const int myi = i0 + isub * 32 + n32;
  const unsigned int Ri2u = RT2[(size_t)myi * NH + head];
  h2 Ri2; __builtin_memcpy(&Ri2, &Ri2u, 4);
  const uint4* bp4 = (const uint4*)(bits + (size_t)myi * (N / 32) + js * 32);

  frag_c16 acc = {0.f, 0.f, 0.f, 0.f, 0.f, 0.f, 0.f, 0.f,
                  0.f, 0.f, 0.f, 0.f, 0.f, 0.f, 0.f, 0.f};
  frag_c16 accl = {0.f, 0.f, 0.f, 0.f, 0.f, 0.f, 0.f, 0.f,
                   0.f, 0.f, 0.f, 0.f, 0.f, 0.f, 0.f, 0.f};
  frag_f16 fone;
#pragma unroll
  for (int u = 0; u < 8; ++u) fone[u] = (_Float16)1.0f;

  const int sr = t >> 2, ss0 = t & 3;  // gT staging persona: row sr, granules ss0+4s
  const unsigned short* gsrc = gT + (size_t)(hp * 64 + sr) * N + js * 1024;

  {  // stage B/D slab once (2 heads x 1024 fp16 x 2 planes = 8 KB)
    const int hsel = t >> 7, idx = t & 127;
    sBD[0][hsel][idx] =
        ((const uint4*)(BT + (size_t)(hp * 2 + hsel) * N + js * 1024))[idx];
    sBD[1][hsel][idx] =
        ((const uint4*)(DT + (size_t)(hp * 2 + hsel) * N + js * 1024))[idx];
  }
  {  // stage gT chunk 0 (swizzled b128 writes)
    int4 pre[4];
#pragma unroll
    for (int s = 0; s < 4; ++s)
      pre[s] = *(const int4*)(gsrc + (ss0 + s * 4) * 8);
#pragma unroll
    for (int s = 0; s < 4; ++s) {
      const int seg = ss0 + s * 4;
      *(int4*)&sB[sr][((seg ^ (sr & 15)) * 8)] = pre[s];
    }
  }
  __syncthreads();

  for (int c8 = 0; c8 < 8; ++c8) {
    int4 nxt[4];
    if (c8 < 7) {  // register prefetch of next chunk (drains behind compute)
#pragma unroll
      for (int s = 0; s < 4; ++s)
        nxt[s] = *(const int4*)(gsrc + (c8 + 1) * 128 + (ss0 + s * 4) * 8);
    }
    const uint4 bw = bp4[c8];
    const unsigned int bwa[4] = {bw.x, bw.y, bw.z, bw.w};
#pragma unroll
    for (int ss = 0; ss < 8; ++ss) {
      const uint4 Bv = sBD[0][hd][c8 * 16 + ss * 2 + kh];  // broadcast read
      const uint4 Dv = sBD[1][hd][c8 * 16 + ss * 2 + kh];
      const unsigned int mb = (bwa[ss >> 1] >> (((ss & 1) << 4) + (kh << 3))) & 0xFFu;
      const unsigned int bu[4] = {Bv.x, Bv.y, Bv.z, Bv.w};
      const unsigned int du[4] = {Dv.x, Dv.y, Dv.z, Dv.w};
      unsigned int packed[4];
#pragma unroll
      for (int p = 0; p < 4; ++p) {
        h2 hB, hD;
        __builtin_memcpy(&hB, &bu[p], 4);
        __builtin_memcpy(&hD, &du[p], 4);
        const h2 wm = __builtin_elementwise_max(hB, Ri2 * hD);  // pk_mul + pk_max
        unsigned int wp; __builtin_memcpy(&wp, &wm, 4);
        const unsigned int d  = (mb >> (2 * p)) & 3u;
        const unsigned int sp = ((d | (d << 15)) & 0x10001u) * 0xFFFFu;
        wp &= sp;
        packed[p] = wp;
      }
      frag_f16 af; __builtin_memcpy(&af, packed, 16);

      const int frow = hd * 32 + n32;
      const int lg   = ss * 2 + kh;                       // logical granule
      const int4 bv  = *(const int4*)&sB[frow][((lg ^ (frow & 15)) * 8)];
      frag_f16 bf; __builtin_memcpy(&bf, &bv, 16);

      acc  = __builtin_amdgcn_mfma_f32_32x32x16_f16(af, bf, acc, 0, 0, 0);
      accl = __builtin_amdgcn_mfma_f32_32x32x16_f16(af, fone, accl, 0, 0, 0);
    }
    if (c8 < 7) {
      __syncthreads();
#pragma unroll
      for (int s = 0; s < 4; ++s) {
        const int seg = ss0 + s * 4;
        *(int4*)&sB[sr][((seg ^ (sr & 15)) * 8)] = nxt[s];
      }
      __syncthreads();
    }
  }

  // ---- epilogue: non-atomic per-js partial stores (wave owns its rows) ----
  float* op = parts + (size_t)js * N * F;
#pragma unroll
  for (int reg = 0; reg < 16; ++reg) {
    const int row = (reg & 3) + 8 * (reg >> 2) + 4 * kh;
    op[(size_t)(i0 + isub * 32 + row) * F + head * HID + n32] = acc[reg];
  }
  if (n32 == 0) {  // accl cols are identical; lane n32==0 stores l for its 8 rows
    float* lp = lparts + (size_t)js * N * NH;
#pragma unroll
    for (int reg = 0; reg < 16; ++reg) {
      const int row = (reg & 3) + 8 * (reg >> 2) + 4 * kh;
      lp[(size_t)(i0 + isub * 32 + row) * NH + head] = accl[reg];
    }
  }
}

// ================= K_NORM: sum partials + normalize =================
__global__ __launch_bounds__(256) void k_norm(const float* __restrict__ parts,
                                              const float* __restrict__ lparts,
                                              float* __restrict__ out) {
  const int idx = blockIdx.x * 256 + threadIdx.x;  // float4 index over N*F/4
  const int i = idx >> 6, fq = idx & 63;
  const int hh = fq >> 3;
  float l = 0.f;
  float4 v = make_float4(0.f, 0.f, 0.f, 0.f);
#pragma unroll
  for (int js = 0; js < NSPLIT; ++js) {
    l += lparts[(size_t)js * N * NH + (size_t)i * NH + hh];
    const float4 p = *(const float4*)(parts + (size_t)js * N * F + (size_t)idx * 4);
    v.x += p.x; v.y += p.y; v.z += p.z; v.w += p.w;
  }
  const float inv = 1.f / l;
  v.x *= inv; v.y *= inv; v.z *= inv; v.w *= inv;
  *(float4*)(out + (size_t)idx * 4) = v;
}

extern "C" void kernel_launch(void* const* d_in, const int* in_sizes, int n_in,
                              void* d_out, int out_size, void* d_ws, size_t ws_size,
                              hipStream_t stream) {
  const float* h   = (const float*)d_in[0];
  const float* W   = (const float*)d_in[1];
  const float* a   = (const float*)d_in[2];
  const int*   adj = (const int*)d_in[3];
  float* out = (float*)d_out;

  // workspace (~21 MB)
  char* ws = (char*)d_ws;
  unsigned short* gT = (unsigned short*)ws;  ws += (size_t)N * F * 2;        // 2 MB
  unsigned int* bits = (unsigned int*)ws;    ws += (size_t)N * (N / 32) * 4; // 2 MB
  unsigned int* RT2 = (unsigned int*)ws;     ws += (size_t)N * NH * 4;
  unsigned short* BT = (unsigned short*)ws;  ws += (size_t)N * NH * 2;
  unsigned short* DT = (unsigned short*)ws;  ws += (size_t)N * NH * 2;
  float* U    = (float*)ws;                  ws += 16 * F * 4;
  float* parts  = (float*)ws;                ws += (size_t)NSPLIT * N * F * 4;  // 16 MB
  float* lparts = (float*)ws;                ws += (size_t)NSPLIT * N * NH * 4; // 512 KB

  k_u<<<dim3(16), dim3(256), 0, stream>>>(W, a, U);
  k_bits<<<dim3(N / 2), dim3(256), 0, stream>>>(adj, bits);
  k_sln<<<dim3(N / 16), dim3(256), 0, stream>>>(h, U, RT2, BT, DT);
  k_gemm<<<dim3((N / 16) * (F / 16) / 4, 1, 1), dim3(256), 0, stream>>>(h, W, gT);
  k_agg<<<dim3((N / TI) * 4 * NSPLIT), dim3(256), 0, stream>>>(
      gT, RT2, BT, DT, bits, parts, lparts);
  k_norm<<<dim3(N * F / 4 / 256), dim3(256), 0, stream>>>(parts, lparts, out);
}

// Round 6
// 160.212 us; speedup vs baseline: 1.1218x; 1.1218x over previous
//
#include <hip/hip_runtime.h>
#include <math.h>

constexpr int N   = 4096;   // nodes
constexpr int F   = 256;    // IN_FEAT (= NH*HID)
constexpr int NH  = 8;      // heads
constexpr int HID = 32;     // hidden per head
constexpr float SLOPE = 0.2f;

using h2       = __attribute__((ext_vector_type(2))) _Float16;
using frag_f16 = __attribute__((ext_vector_type(8))) _Float16;  // 4 VGPRs
using frag_cd  = __attribute__((ext_vector_type(4))) float;
using frag_c16 = __attribute__((ext_vector_type(16))) float;

__device__ inline unsigned short f2h(float x) {
  _Float16 v = (_Float16)x;
  unsigned short u; __builtin_memcpy(&u, &v, 2); return u;
}

// ================= K_U: U[c][k] = sum_f W[head*32+f][k] * a[side*32+f] =================
__global__ __launch_bounds__(256) void k_u(const float* __restrict__ W,
                                           const float* __restrict__ a,
                                           float* __restrict__ U) {
  const int c = blockIdx.x, k = threadIdx.x;
  const int head = c & 7, side = c >> 3;
  float acc = 0.f;
#pragma unroll
  for (int f = 0; f < 32; ++f)
    acc += W[(size_t)(head * 32 + f) * F + k] * a[side * 32 + f];
  U[c * F + k] = acc;
}

// ================= K_FRONT: everything before aggregation (ZERO LDS) =================
// [0,256):      s = h@U (U from global, L1-hot) -> RT2, BT, DT
// [256,1280):   gT = (h @ W^T)^T fp16 via MFMA, fp32->fp16 cast in-register
// [1280,3328):  adjacency bitmask: wave-contiguous int4 loads + shfl_xor packing
__global__ __launch_bounds__(256) void k_front(const float* __restrict__ h,
                                               const float* __restrict__ W,
                                               const float* __restrict__ U,
                                               const int* __restrict__ adj,
                                               unsigned int* __restrict__ RT2,
                                               unsigned short* __restrict__ BT,
                                               unsigned short* __restrict__ DT,
                                               unsigned short* __restrict__ gT,
                                               unsigned int* __restrict__ bits) {
  const int b = blockIdx.x, t = threadIdx.x;
  if (b < 256) {
    // ---- s-part: thread (r,c); h-row reads broadcast across the 16 c-threads ----
    const int i0 = b * 16;
    const int r = t >> 4, c = t & 15;
    const float4* hp = (const float4*)(h + (size_t)(i0 + r) * F);
    const float4* up = (const float4*)(U + (size_t)c * F);
    float acc = 0.f;
#pragma unroll
    for (int k4 = 0; k4 < 64; ++k4) {
      const float4 hv = hp[k4];
      const float4 uv = up[k4];
      acc += hv.x * uv.x + hv.y * uv.y + hv.z * uv.z + hv.w * uv.w;
    }
    const int n = i0 + r;
    if (c < 8) {
      const unsigned int r16 = f2h(__expf(-0.8f * acc));
      RT2[(size_t)n * NH + c] = (r16 << 16) | r16;
    } else {
      const int hd = c - 8;
      BT[(size_t)hd * N + n] = f2h(__expf(acc));
      DT[(size_t)hd * N + n] = f2h(__expf(SLOPE * acc));
    }
  } else if (b < 1280) {
    // ---- gT GEMM: one wave per 16x16 tile, in-register fp32->fp16 ----
    const int lane = t & 63;
    const int tile = (b - 256) * 4 + (t >> 6);
    const int mt = tile >> 4, nt = tile & 15;
    const int m0 = mt * 16, n0 = nt * 16;
    const int n16 = lane & 15, quad = lane >> 4;
    frag_cd acc = {0.f, 0.f, 0.f, 0.f};
    const float* ap = h + (size_t)(m0 + n16) * F + quad * 8;
    const float* bp = W + (size_t)(n0 + n16) * F + quad * 8;
#pragma unroll
    for (int ks = 0; ks < F / 32; ++ks) {
      const float4 a0 = *(const float4*)(ap + ks * 32);
      const float4 a1 = *(const float4*)(ap + ks * 32 + 4);
      const float4 b0 = *(const float4*)(bp + ks * 32);
      const float4 b1 = *(const float4*)(bp + ks * 32 + 4);
      const frag_f16 af = {(_Float16)a0.x, (_Float16)a0.y, (_Float16)a0.z, (_Float16)a0.w,
                           (_Float16)a1.x, (_Float16)a1.y, (_Float16)a1.z, (_Float16)a1.w};
      const frag_f16 bf = {(_Float16)b0.x, (_Float16)b0.y, (_Float16)b0.z, (_Float16)b0.w,
                           (_Float16)b1.x, (_Float16)b1.y, (_Float16)b1.z, (_Float16)b1.w};
      acc = __builtin_amdgcn_mfma_f32_16x16x32_f16(af, bf, acc, 0, 0, 0);
    }
    unsigned short tmp[4];
#pragma unroll
    for (int reg = 0; reg < 4; ++reg) tmp[reg] = f2h(acc[reg]);
    *(int2*)(gT + (size_t)(n0 + n16) * N + m0 + quad * 4) = *(int2*)tmp;
  } else {
    // ---- bitmask: wave-contiguous loads. Lane l reads int4 (4 adj ints) at
    // lane-consecutive addresses (1 KB/instr, fully coalesced), packs a nibble,
    // 3-round shfl_xor OR-butterfly assembles the 32-bit word in groups of 8.
    const int lane = t & 63;
    const int wv   = t >> 6;
    const int row  = (b - 1280) * 2 + (wv >> 1);
    const int half = wv & 1;  // each wave covers 2048 ints = 8 KB
    const int4* src4 = (const int4*)(adj + (size_t)row * N) + half * 512 + lane;
    const int shamt = (lane & 7) * 4;
    unsigned int* dstw = bits + (size_t)row * (N / 32) + half * 64 + (lane >> 3);
#pragma unroll
    for (int it = 0; it < 8; ++it) {
      const int4 v4 = src4[it * 64];
      unsigned int v = ((unsigned)v4.x | ((unsigned)v4.y << 1) |
                        ((unsigned)v4.z << 2) | ((unsigned)v4.w << 3)) << shamt;
      v |= (unsigned)__shfl_xor((int)v, 1);
      v |= (unsigned)__shfl_xor((int)v, 2);
      v |= (unsigned)__shfl_xor((int)v, 4);
      if ((lane & 7) == 0) dstw[it * 8] = v;
    }
  }
}

// ================= K_AGG: 64i-tile 32x32 fp16-MFMA flash aggregation =================
// block = 64 i x head-pair x 1/8 j (512 j); waves: (hd = wv>>1, isub = wv&1).
// NSPLIT=8 + launch_bounds(256,6): 6 resident blocks/CU (24 waves) for latency
// hiding (round-4 PMC: all pipes <40% busy -> stall-bound at 4 blocks/CU).
// sB: proven 140-short-stride layout (2-way-free banks); int2-pair reads.
// B/D staging: 128 threads x BOTH planes (fixes round-5 half-coverage NaN).
constexpr int TI = 64;
constexpr int NSPLIT = 8;

__global__ __launch_bounds__(256, 6) void k_agg(
    const unsigned short* __restrict__ gT,
    const unsigned int* __restrict__ RT2,
    const unsigned short* __restrict__ BT, const unsigned short* __restrict__ DT,
    const unsigned int* __restrict__ bits,
    float* __restrict__ parts, float* __restrict__ lparts) {
  __shared__ __align__(16) unsigned short sB[64][140];   // gT chunk, row=f, col=j
  __shared__ __align__(16) uint4 sBD[2][2][64];          // [B/D][head][512 fp16]

  const int t    = threadIdx.x;
  const int lane = t & 63;
  const int wv   = t >> 6;
  const int isub = wv & 1;
  const int hd   = wv >> 1;
  const int b    = blockIdx.x;
  const int hp   = b & 3;
  const int js   = (b >> 2) & (NSPLIT - 1);
  const int i0   = (b >> 5) * TI;
  const int head = hp * 2 + hd;

  const int n32 = lane & 31;
  const int kh  = lane >> 5;

  const int myi = i0 + isub * 32 + n32;
  const unsigned int Ri2u = RT2[(size_t)myi * NH + head];
  h2 Ri2; __builtin_memcpy(&Ri2, &Ri2u, 4);
  const uint4* bp4 = (const uint4*)(bits + (size_t)myi * (N / 32) + js * 16);

  frag_c16 acc = {0.f, 0.f, 0.f, 0.f, 0.f, 0.f, 0.f, 0.f,
                  0.f, 0.f, 0.f, 0.f, 0.f, 0.f, 0.f, 0.f};
  frag_c16 accl = {0.f, 0.f, 0.f, 0.f, 0.f, 0.f, 0.f, 0.f,
                   0.f, 0.f, 0.f, 0.f, 0.f, 0.f, 0.f, 0.f};
  frag_f16 fone;
#pragma unroll
  for (int u = 0; u < 8; ++u) fone[u] = (_Float16)1.0f;

  const int sr = t >> 2, ss0 = t & 3;  // gT staging persona
  const unsigned short* gsrc = gT + (size_t)(hp * 64 + sr) * N + js * 512;

  {  // stage B/D slab once: 128 threads, each writes BOTH planes
    if (t < 128) {
      const int hsel = t >> 6, idx = t & 63;   // 2 heads x 64 uint4 = full extent
      sBD[0][hsel][idx] =
          ((const uint4*)(BT + (size_t)(hp * 2 + hsel) * N + js * 512))[idx];
      sBD[1][hsel][idx] =
          ((const uint4*)(DT + (size_t)(hp * 2 + hsel) * N + js * 512))[idx];
    }
  }
  {  // stage gT chunk 0
    int4 pre[4];
#pragma unroll
    for (int s = 0; s < 4; ++s)
      pre[s] = *(const int4*)(gsrc + (ss0 + s * 4) * 8);
#pragma unroll
    for (int s = 0; s < 4; ++s) {
      const int seg = ss0 + s * 4;
      *(int2*)&sB[sr][seg * 8]     = make_int2(pre[s].x, pre[s].y);
      *(int2*)&sB[sr][seg * 8 + 4] = make_int2(pre[s].z, pre[s].w);
    }
  }
  __syncthreads();

  for (int c8 = 0; c8 < 4; ++c8) {
    int4 nxt[4];
    if (c8 < 3) {  // register prefetch of next chunk (drains behind compute)
#pragma unroll
      for (int s = 0; s < 4; ++s)
        nxt[s] = *(const int4*)(gsrc + (c8 + 1) * 128 + (ss0 + s * 4) * 8);
    }
    const uint4 bw = bp4[c8];
    const unsigned int bwa[4] = {bw.x, bw.y, bw.z, bw.w};
#pragma unroll
    for (int ss = 0; ss < 8; ++ss) {
      const int jb = ss * 16 + kh * 8;
      const uint4 Bv = sBD[0][hd][c8 * 16 + ss * 2 + kh];  // broadcast read
      const uint4 Dv = sBD[1][hd][c8 * 16 + ss * 2 + kh];
      const unsigned int mb = (bwa[ss >> 1] >> (((ss & 1) << 4) + (kh << 3))) & 0xFFu;
      const unsigned int bu[4] = {Bv.x, Bv.y, Bv.z, Bv.w};
      const unsigned int du[4] = {Dv.x, Dv.y, Dv.z, Dv.w};
      unsigned int packed[4];
#pragma unroll
      for (int p = 0; p < 4; ++p) {
        h2 hB, hD;
        __builtin_memcpy(&hB, &bu[p], 4);
        __builtin_memcpy(&hD, &du[p], 4);
        const h2 wm = __builtin_elementwise_max(hB, Ri2 * hD);  // pk_mul + pk_max
        unsigned int wp; __builtin_memcpy(&wp, &wm, 4);
        const unsigned int d  = (mb >> (2 * p)) & 3u;
        const unsigned int sp = ((d | (d << 15)) & 0x10001u) * 0xFFFFu;
        wp &= sp;
        packed[p] = wp;
      }
      frag_f16 af; __builtin_memcpy(&af, packed, 16);

      const int frow = hd * 32 + n32;
      const int2 blo = *(const int2*)&sB[frow][jb];
      const int2 bhi = *(const int2*)&sB[frow][jb + 4];
      const int bt[4] = {blo.x, blo.y, bhi.x, bhi.y};
      frag_f16 bf; __builtin_memcpy(&bf, bt, 16);

      acc  = __builtin_amdgcn_mfma_f32_32x32x16_f16(af, bf, acc, 0, 0, 0);
      accl = __builtin_amdgcn_mfma_f32_32x32x16_f16(af, fone, accl, 0, 0, 0);
    }
    if (c8 < 3) {
      __syncthreads();
#pragma unroll
      for (int s = 0; s < 4; ++s) {
        const int seg = ss0 + s * 4;
        *(int2*)&sB[sr][seg * 8]     = make_int2(nxt[s].x, nxt[s].y);
        *(int2*)&sB[sr][seg * 8 + 4] = make_int2(nxt[s].z, nxt[s].w);
      }
      __syncthreads();
    }
  }

  // ---- epilogue: non-atomic per-js partial stores (wave owns its rows) ----
  float* op = parts + (size_t)js * N * F;
#pragma unroll
  for (int reg = 0; reg < 16; ++reg) {
    const int row = (reg & 3) + 8 * (reg >> 2) + 4 * kh;
    op[(size_t)(i0 + isub * 32 + row) * F + head * HID + n32] = acc[reg];
  }
  if (n32 == 0) {  // accl cols are identical; lane n32==0 stores l for its 8 rows
    float* lp = lparts + (size_t)js * N * NH;
#pragma unroll
    for (int reg = 0; reg < 16; ++reg) {
      const int row = (reg & 3) + 8 * (reg >> 2) + 4 * kh;
      lp[(size_t)(i0 + isub * 32 + row) * NH + head] = accl[reg];
    }
  }
}

// ================= K_NORM: sum partials + normalize =================
__global__ __launch_bounds__(256) void k_norm(const float* __restrict__ parts,
                                              const float* __restrict__ lparts,
                                              float* __restrict__ out) {
  const int idx = blockIdx.x * 256 + threadIdx.x;  // float4 index over N*F/4
  const int i = idx >> 6, fq = idx & 63;
  const int hh = fq >> 3;
  float l = 0.f;
  float4 v = make_float4(0.f, 0.f, 0.f, 0.f);
#pragma unroll
  for (int js = 0; js < NSPLIT; ++js) {
    l += lparts[(size_t)js * N * NH + (size_t)i * NH + hh];
    const float4 p = *(const float4*)(parts + (size_t)js * N * F + (size_t)idx * 4);
    v.x += p.x; v.y += p.y; v.z += p.z; v.w += p.w;
  }
  const float inv = 1.f / l;
  v.x *= inv; v.y *= inv; v.z *= inv; v.w *= inv;
  *(float4*)(out + (size_t)idx * 4) = v;
}

extern "C" void kernel_launch(void* const* d_in, const int* in_sizes, int n_in,
                              void* d_out, int out_size, void* d_ws, size_t ws_size,
                              hipStream_t stream) {
  const float* h   = (const float*)d_in[0];
  const float* W   = (const float*)d_in[1];
  const float* a   = (const float*)d_in[2];
  const int*   adj = (const int*)d_in[3];
  float* out = (float*)d_out;

  // workspace (~39 MB)
  char* ws = (char*)d_ws;
  unsigned short* gT = (unsigned short*)ws;  ws += (size_t)N * F * 2;        // 2 MB
  unsigned int* bits = (unsigned int*)ws;    ws += (size_t)N * (N / 32) * 4; // 2 MB
  unsigned int* RT2 = (unsigned int*)ws;     ws += (size_t)N * NH * 4;
  unsigned short* BT = (unsigned short*)ws;  ws += (size_t)N * NH * 2;
  unsigned short* DT = (unsigned short*)ws;  ws += (size_t)N * NH * 2;
  float* U    = (float*)ws;                  ws += 16 * F * 4;
  float* parts  = (float*)ws;                ws += (size_t)NSPLIT * N * F * 4;  // 33.5 MB
  float* lparts = (float*)ws;                ws += (size_t)NSPLIT * N * NH * 4; // 1 MB

  k_u<<<dim3(16), dim3(256), 0, stream>>>(W, a, U);
  k_front<<<dim3(3328), dim3(256), 0, stream>>>(h, W, U, adj, RT2, BT, DT, gT, bits);
  k_agg<<<dim3((N / TI) * 4 * NSPLIT), dim3(256), 0, stream>>>(
      gT, RT2, BT, DT, bits, parts, lparts);
  k_norm<<<dim3(N * F / 4 / 256), dim3(256), 0, stream>>>(parts, lparts, out);
}

// Round 7
// 156.563 us; speedup vs baseline: 1.1479x; 1.0233x over previous
//
#include <hip/hip_runtime.h>
#include <math.h>

constexpr int N   = 4096;   // nodes
constexpr int F   = 256;    // IN_FEAT (= NH*HID)
constexpr int NH  = 8;      // heads
constexpr int HID = 32;     // hidden per head
constexpr float SLOPE = 0.2f;

using h2       = __attribute__((ext_vector_type(2))) _Float16;
using frag_f16 = __attribute__((ext_vector_type(8))) _Float16;  // 4 VGPRs
using frag_cd  = __attribute__((ext_vector_type(4))) float;
using frag_c16 = __attribute__((ext_vector_type(16))) float;

__device__ inline unsigned short f2h(float x) {
  _Float16 v = (_Float16)x;
  unsigned short u; __builtin_memcpy(&u, &v, 2); return u;
}

// ================= K_U: U[c][k] = sum_f W[head*32+f][k] * a[side*32+f] =================
__global__ __launch_bounds__(256) void k_u(const float* __restrict__ W,
                                           const float* __restrict__ a,
                                           float* __restrict__ U) {
  const int c = blockIdx.x, k = threadIdx.x;
  const int head = c & 7, side = c >> 3;
  float acc = 0.f;
#pragma unroll
  for (int f = 0; f < 32; ++f)
    acc += W[(size_t)(head * 32 + f) * F + k] * a[side * 32 + f];
  U[c * F + k] = acc;
}

// ================= K_FRONT: everything before aggregation (ZERO LDS) =================
// [0,256):      s = h@U (U from global, L1-hot) -> RT2, BT, DT
// [256,1280):   gT = (h @ W^T)^T fp16 via MFMA, fp32->fp16 cast in-register
// [1280,3328):  adjacency bitmask: wave-contiguous int4 loads + shfl_xor packing
__global__ __launch_bounds__(256) void k_front(const float* __restrict__ h,
                                               const float* __restrict__ W,
                                               const float* __restrict__ U,
                                               const int* __restrict__ adj,
                                               unsigned int* __restrict__ RT2,
                                               unsigned short* __restrict__ BT,
                                               unsigned short* __restrict__ DT,
                                               unsigned short* __restrict__ gT,
                                               unsigned int* __restrict__ bits) {
  const int b = blockIdx.x, t = threadIdx.x;
  if (b < 256) {
    // ---- s-part: thread (r,c); h-row reads broadcast across the 16 c-threads ----
    const int i0 = b * 16;
    const int r = t >> 4, c = t & 15;
    const float4* hp = (const float4*)(h + (size_t)(i0 + r) * F);
    const float4* up = (const float4*)(U + (size_t)c * F);
    float acc = 0.f;
#pragma unroll
    for (int k4 = 0; k4 < 64; ++k4) {
      const float4 hv = hp[k4];
      const float4 uv = up[k4];
      acc += hv.x * uv.x + hv.y * uv.y + hv.z * uv.z + hv.w * uv.w;
    }
    const int n = i0 + r;
    if (c < 8) {
      const unsigned int r16 = f2h(__expf(-0.8f * acc));
      RT2[(size_t)n * NH + c] = (r16 << 16) | r16;
    } else {
      const int hd = c - 8;
      BT[(size_t)hd * N + n] = f2h(__expf(acc));
      DT[(size_t)hd * N + n] = f2h(__expf(SLOPE * acc));
    }
  } else if (b < 1280) {
    // ---- gT GEMM: one wave per 16x16 tile, in-register fp32->fp16 ----
    const int lane = t & 63;
    const int tile = (b - 256) * 4 + (t >> 6);
    const int mt = tile >> 4, nt = tile & 15;
    const int m0 = mt * 16, n0 = nt * 16;
    const int n16 = lane & 15, quad = lane >> 4;
    frag_cd acc = {0.f, 0.f, 0.f, 0.f};
    const float* ap = h + (size_t)(m0 + n16) * F + quad * 8;
    const float* bp = W + (size_t)(n0 + n16) * F + quad * 8;
#pragma unroll
    for (int ks = 0; ks < F / 32; ++ks) {
      const float4 a0 = *(const float4*)(ap + ks * 32);
      const float4 a1 = *(const float4*)(ap + ks * 32 + 4);
      const float4 b0 = *(const float4*)(bp + ks * 32);
      const float4 b1 = *(const float4*)(bp + ks * 32 + 4);
      const frag_f16 af = {(_Float16)a0.x, (_Float16)a0.y, (_Float16)a0.z, (_Float16)a0.w,
                           (_Float16)a1.x, (_Float16)a1.y, (_Float16)a1.z, (_Float16)a1.w};
      const frag_f16 bf = {(_Float16)b0.x, (_Float16)b0.y, (_Float16)b0.z, (_Float16)b0.w,
                           (_Float16)b1.x, (_Float16)b1.y, (_Float16)b1.z, (_Float16)b1.w};
      acc = __builtin_amdgcn_mfma_f32_16x16x32_f16(af, bf, acc, 0, 0, 0);
    }
    unsigned short tmp[4];
#pragma unroll
    for (int reg = 0; reg < 4; ++reg) tmp[reg] = f2h(acc[reg]);
    *(int2*)(gT + (size_t)(n0 + n16) * N + m0 + quad * 4) = *(int2*)tmp;
  } else {
    // ---- bitmask: wave-contiguous loads. Lane l reads int4 (4 adj ints) at
    // lane-consecutive addresses (1 KB/instr, fully coalesced), packs a nibble,
    // 3-round shfl_xor OR-butterfly assembles the 32-bit word in groups of 8.
    const int lane = t & 63;
    const int wv   = t >> 6;
    const int row  = (b - 1280) * 2 + (wv >> 1);
    const int half = wv & 1;  // each wave covers 2048 ints = 8 KB
    const int4* src4 = (const int4*)(adj + (size_t)row * N) + half * 512 + lane;
    const int shamt = (lane & 7) * 4;
    unsigned int* dstw = bits + (size_t)row * (N / 32) + half * 64 + (lane >> 3);
#pragma unroll
    for (int it = 0; it < 8; ++it) {
      const int4 v4 = src4[it * 64];
      unsigned int v = ((unsigned)v4.x | ((unsigned)v4.y << 1) |
                        ((unsigned)v4.z << 2) | ((unsigned)v4.w << 3)) << shamt;
      v |= (unsigned)__shfl_xor((int)v, 1);
      v |= (unsigned)__shfl_xor((int)v, 2);
      v |= (unsigned)__shfl_xor((int)v, 4);
      if ((lane & 7) == 0) dstw[it * 8] = v;
    }
  }
}

// ================= K_AGG: 64i-tile 32x32 fp16-MFMA flash aggregation =================
// block = 64 i x head-pair x 1/4 j (1024 j); waves: (hd = wv>>1, isub = wv&1).
// NSPLIT=4 (proven); latency-stall fixes this round:
//  - depth-1 prefetch of the bits word (kills per-chunk global-load stall)
//  - half-batch register hoist of B/D LDS broadcast reads (batches 8 b128
//    issues ahead of their use instead of 16 serial ~120-cyc stalls/chunk)
constexpr int TI = 64;
constexpr int NSPLIT = 4;

__global__ __launch_bounds__(256, 4) void k_agg(
    const unsigned short* __restrict__ gT,
    const unsigned int* __restrict__ RT2,
    const unsigned short* __restrict__ BT, const unsigned short* __restrict__ DT,
    const unsigned int* __restrict__ bits,
    float* __restrict__ parts, float* __restrict__ lparts) {
  __shared__ __align__(16) unsigned short sB[64][140];   // gT chunk, row=f, col=j
  __shared__ __align__(16) uint4 sBD[2][2][128];         // [B/D][head][1024 fp16]

  const int t    = threadIdx.x;
  const int lane = t & 63;
  const int wv   = t >> 6;
  const int isub = wv & 1;
  const int hd   = wv >> 1;
  const int b    = blockIdx.x;
  const int hp   = b & 3;
  const int js   = (b >> 2) & (NSPLIT - 1);
  const int i0   = (b >> 4) * TI;
  const int head = hp * 2 + hd;

  const int n32 = lane & 31;
  const int kh  = lane >> 5;

  const int myi = i0 + isub * 32 + n32;
  const unsigned int Ri2u = RT2[(size_t)myi * NH + head];
  h2 Ri2; __builtin_memcpy(&Ri2, &Ri2u, 4);
  const uint4* bp4 = (const uint4*)(bits + (size_t)myi * (N / 32) + js * 32);

  frag_c16 acc = {0.f, 0.f, 0.f, 0.f, 0.f, 0.f, 0.f, 0.f,
                  0.f, 0.f, 0.f, 0.f, 0.f, 0.f, 0.f, 0.f};
  frag_c16 accl = {0.f, 0.f, 0.f, 0.f, 0.f, 0.f, 0.f, 0.f,
                   0.f, 0.f, 0.f, 0.f, 0.f, 0.f, 0.f, 0.f};
  frag_f16 fone;
#pragma unroll
  for (int u = 0; u < 8; ++u) fone[u] = (_Float16)1.0f;

  const int sr = t >> 2, ss0 = t & 3;  // gT staging persona
  const unsigned short* gsrc = gT + (size_t)(hp * 64 + sr) * N + js * 1024;

  {  // stage B/D slab once (2 heads x 1024 fp16 x 2 planes = 8 KB)
    const int hsel = t >> 7, idx = t & 127;
    sBD[0][hsel][idx] =
        ((const uint4*)(BT + (size_t)(hp * 2 + hsel) * N + js * 1024))[idx];
    sBD[1][hsel][idx] =
        ((const uint4*)(DT + (size_t)(hp * 2 + hsel) * N + js * 1024))[idx];
  }
  {  // stage gT chunk 0
    int4 pre[4];
#pragma unroll
    for (int s = 0; s < 4; ++s)
      pre[s] = *(const int4*)(gsrc + (ss0 + s * 4) * 8);
#pragma unroll
    for (int s = 0; s < 4; ++s) {
      const int seg = ss0 + s * 4;
      *(int2*)&sB[sr][seg * 8]     = make_int2(pre[s].x, pre[s].y);
      *(int2*)&sB[sr][seg * 8 + 4] = make_int2(pre[s].z, pre[s].w);
    }
  }
  __syncthreads();

  uint4 bw = bp4[0];  // depth-1 prefetched bits word
  for (int c8 = 0; c8 < 8; ++c8) {
    const uint4 bwn = (c8 < 7) ? bp4[c8 + 1] : bw;  // prefetch next chunk's bits
    int4 nxt[4];
    if (c8 < 7) {  // register prefetch of next gT chunk (drains behind compute)
#pragma unroll
      for (int s = 0; s < 4; ++s)
        nxt[s] = *(const int4*)(gsrc + (c8 + 1) * 128 + (ss0 + s * 4) * 8);
    }
    const unsigned int bwa[4] = {bw.x, bw.y, bw.z, bw.w};
#pragma unroll
    for (int half = 0; half < 2; ++half) {
      // batch-hoist this half's B/D broadcast reads (8 x ds_read_b128)
      uint4 Bva[4], Dva[4];
#pragma unroll
      for (int q = 0; q < 4; ++q) {
        const int ss = half * 4 + q;
        Bva[q] = sBD[0][hd][c8 * 16 + ss * 2 + kh];
        Dva[q] = sBD[1][hd][c8 * 16 + ss * 2 + kh];
      }
#pragma unroll
      for (int q = 0; q < 4; ++q) {
        const int ss = half * 4 + q;
        const int jb = ss * 16 + kh * 8;
        const unsigned int mb = (bwa[ss >> 1] >> (((ss & 1) << 4) + (kh << 3))) & 0xFFu;
        const unsigned int bu[4] = {Bva[q].x, Bva[q].y, Bva[q].z, Bva[q].w};
        const unsigned int du[4] = {Dva[q].x, Dva[q].y, Dva[q].z, Dva[q].w};
        unsigned int packed[4];
#pragma unroll
        for (int p = 0; p < 4; ++p) {
          h2 hB, hD;
          __builtin_memcpy(&hB, &bu[p], 4);
          __builtin_memcpy(&hD, &du[p], 4);
          const h2 wm = __builtin_elementwise_max(hB, Ri2 * hD);  // pk_mul + pk_max
          unsigned int wp; __builtin_memcpy(&wp, &wm, 4);
          const unsigned int d  = (mb >> (2 * p)) & 3u;
          const unsigned int sp = ((d | (d << 15)) & 0x10001u) * 0xFFFFu;
          wp &= sp;
          packed[p] = wp;
        }
        frag_f16 af; __builtin_memcpy(&af, packed, 16);

        const int frow = hd * 32 + n32;
        const int2 blo = *(const int2*)&sB[frow][jb];
        const int2 bhi = *(const int2*)&sB[frow][jb + 4];
        const int bt[4] = {blo.x, blo.y, bhi.x, bhi.y};
        frag_f16 bf; __builtin_memcpy(&bf, bt, 16);

        acc  = __builtin_amdgcn_mfma_f32_32x32x16_f16(af, bf, acc, 0, 0, 0);
        accl = __builtin_amdgcn_mfma_f32_32x32x16_f16(af, fone, accl, 0, 0, 0);
      }
    }
    if (c8 < 7) {
      __syncthreads();
#pragma unroll
      for (int s = 0; s < 4; ++s) {
        const int seg = ss0 + s * 4;
        *(int2*)&sB[sr][seg * 8]     = make_int2(nxt[s].x, nxt[s].y);
        *(int2*)&sB[sr][seg * 8 + 4] = make_int2(nxt[s].z, nxt[s].w);
      }
      __syncthreads();
    }
    bw = bwn;
  }

  // ---- epilogue: non-atomic per-js partial stores (wave owns its rows) ----
  float* op = parts + (size_t)js * N * F;
#pragma unroll
  for (int reg = 0; reg < 16; ++reg) {
    const int row = (reg & 3) + 8 * (reg >> 2) + 4 * kh;
    op[(size_t)(i0 + isub * 32 + row) * F + head * HID + n32] = acc[reg];
  }
  if (n32 == 0) {  // accl cols are identical; lane n32==0 stores l for its 8 rows
    float* lp = lparts + (size_t)js * N * NH;
#pragma unroll
    for (int reg = 0; reg < 16; ++reg) {
      const int row = (reg & 3) + 8 * (reg >> 2) + 4 * kh;
      lp[(size_t)(i0 + isub * 32 + row) * NH + head] = accl[reg];
    }
  }
}

// ================= K_NORM: sum partials + normalize =================
__global__ __launch_bounds__(256) void k_norm(const float* __restrict__ parts,
                                              const float* __restrict__ lparts,
                                              float* __restrict__ out) {
  const int idx = blockIdx.x * 256 + threadIdx.x;  // float4 index over N*F/4
  const int i = idx >> 6, fq = idx & 63;
  const int hh = fq >> 3;
  float l = 0.f;
  float4 v = make_float4(0.f, 0.f, 0.f, 0.f);
#pragma unroll
  for (int js = 0; js < NSPLIT; ++js) {
    l += lparts[(size_t)js * N * NH + (size_t)i * NH + hh];
    const float4 p = *(const float4*)(parts + (size_t)js * N * F + (size_t)idx * 4);
    v.x += p.x; v.y += p.y; v.z += p.z; v.w += p.w;
  }
  const float inv = 1.f / l;
  v.x *= inv; v.y *= inv; v.z *= inv; v.w *= inv;
  *(float4*)(out + (size_t)idx * 4) = v;
}

extern "C" void kernel_launch(void* const* d_in, const int* in_sizes, int n_in,
                              void* d_out, int out_size, void* d_ws, size_t ws_size,
                              hipStream_t stream) {
  const float* h   = (const float*)d_in[0];
  const float* W   = (const float*)d_in[1];
  const float* a   = (const float*)d_in[2];
  const int*   adj = (const int*)d_in[3];
  float* out = (float*)d_out;

  // workspace (~21 MB)
  char* ws = (char*)d_ws;
  unsigned short* gT = (unsigned short*)ws;  ws += (size_t)N * F * 2;        // 2 MB
  unsigned int* bits = (unsigned int*)ws;    ws += (size_t)N * (N / 32) * 4; // 2 MB
  unsigned int* RT2 = (unsigned int*)ws;     ws += (size_t)N * NH * 4;
  unsigned short* BT = (unsigned short*)ws;  ws += (size_t)N * NH * 2;
  unsigned short* DT = (unsigned short*)ws;  ws += (size_t)N * NH * 2;
  float* U    = (float*)ws;                  ws += 16 * F * 4;
  float* parts  = (float*)ws;                ws += (size_t)NSPLIT * N * F * 4;  // 16 MB
  float* lparts = (float*)ws;                ws += (size_t)NSPLIT * N * NH * 4; // 512 KB

  k_u<<<dim3(16), dim3(256), 0, stream>>>(W, a, U);
  k_front<<<dim3(3328), dim3(256), 0, stream>>>(h, W, U, adj, RT2, BT, DT, gT, bits);
  k_agg<<<dim3((N / TI) * 4 * NSPLIT), dim3(256), 0, stream>>>(
      gT, RT2, BT, DT, bits, parts, lparts);
  k_norm<<<dim3(N * F / 4 / 256), dim3(256), 0, stream>>>(parts, lparts, out);
}

// Round 8
// 152.095 us; speedup vs baseline: 1.1817x; 1.0294x over previous
//
#include <hip/hip_runtime.h>
#include <math.h>

constexpr int N   = 4096;   // nodes
constexpr int F   = 256;    // IN_FEAT (= NH*HID)
constexpr int NH  = 8;      // heads
constexpr int HID = 32;     // hidden per head
constexpr float SLOPE = 0.2f;

using h2       = __attribute__((ext_vector_type(2))) _Float16;
using frag_f16 = __attribute__((ext_vector_type(8))) _Float16;  // 4 VGPRs
using frag_cd  = __attribute__((ext_vector_type(4))) float;
using frag_c16 = __attribute__((ext_vector_type(16))) float;

__device__ inline unsigned short f2h(float x) {
  _Float16 v = (_Float16)x;
  unsigned short u; __builtin_memcpy(&u, &v, 2); return u;
}

// ================= K_U: U[c][k] = sum_f W[head*32+f][k] * a[side*32+f] =================
__global__ __launch_bounds__(256) void k_u(const float* __restrict__ W,
                                           const float* __restrict__ a,
                                           float* __restrict__ U) {
  const int c = blockIdx.x, k = threadIdx.x;
  const int head = c & 7, side = c >> 3;
  float acc = 0.f;
#pragma unroll
  for (int f = 0; f < 32; ++f)
    acc += W[(size_t)(head * 32 + f) * F + k] * a[side * 32 + f];
  U[c * F + k] = acc;
}

// ================= K_FRONT: everything before aggregation (ZERO LDS) =================
// [0,256):      s = h@U (U from global, L1-hot) -> RT2, BT, DT
// [256,1280):   gT2 = (h @ W^T)^T fp16 via MFMA, stored in MFMA-FRAGMENT ORDER:
//               gT2[head][js][c8][ss][lane=kh*32+n32][8]  (k_agg reads b128/lane)
// [1280,3328):  adjacency bitmask: wave-contiguous int4 loads + shfl_xor packing
__global__ __launch_bounds__(256) void k_front(const float* __restrict__ h,
                                               const float* __restrict__ W,
                                               const float* __restrict__ U,
                                               const int* __restrict__ adj,
                                               unsigned int* __restrict__ RT2,
                                               unsigned short* __restrict__ BT,
                                               unsigned short* __restrict__ DT,
                                               unsigned short* __restrict__ gT2,
                                               unsigned int* __restrict__ bits) {
  const int b = blockIdx.x, t = threadIdx.x;
  if (b < 256) {
    // ---- s-part: thread (r,c); h-row reads broadcast across the 16 c-threads ----
    const int i0 = b * 16;
    const int r = t >> 4, c = t & 15;
    const float4* hp = (const float4*)(h + (size_t)(i0 + r) * F);
    const float4* up = (const float4*)(U + (size_t)c * F);
    float acc = 0.f;
#pragma unroll
    for (int k4 = 0; k4 < 64; ++k4) {
      const float4 hv = hp[k4];
      const float4 uv = up[k4];
      acc += hv.x * uv.x + hv.y * uv.y + hv.z * uv.z + hv.w * uv.w;
    }
    const int n = i0 + r;
    if (c < 8) {
      const unsigned int r16 = f2h(__expf(-0.8f * acc));
      RT2[(size_t)n * NH + c] = (r16 << 16) | r16;
    } else {
      const int hd = c - 8;
      BT[(size_t)hd * N + n] = f2h(__expf(acc));
      DT[(size_t)hd * N + n] = f2h(__expf(SLOPE * acc));
    }
  } else if (b < 1280) {
    // ---- gT2 GEMM: one wave per 16x16 tile, in-register fp32->fp16 ----
    const int lane = t & 63;
    const int tile = (b - 256) * 4 + (t >> 6);
    const int mt = tile >> 4, nt = tile & 15;
    const int m0 = mt * 16, n0 = nt * 16;
    const int n16 = lane & 15, quad = lane >> 4;
    frag_cd acc = {0.f, 0.f, 0.f, 0.f};
    const float* ap = h + (size_t)(m0 + n16) * F + quad * 8;
    const float* bp = W + (size_t)(n0 + n16) * F + quad * 8;
#pragma unroll
    for (int ks = 0; ks < F / 32; ++ks) {
      const float4 a0 = *(const float4*)(ap + ks * 32);
      const float4 a1 = *(const float4*)(ap + ks * 32 + 4);
      const float4 b0 = *(const float4*)(bp + ks * 32);
      const float4 b1 = *(const float4*)(bp + ks * 32 + 4);
      const frag_f16 af = {(_Float16)a0.x, (_Float16)a0.y, (_Float16)a0.z, (_Float16)a0.w,
                           (_Float16)a1.x, (_Float16)a1.y, (_Float16)a1.z, (_Float16)a1.w};
      const frag_f16 bf = {(_Float16)b0.x, (_Float16)b0.y, (_Float16)b0.z, (_Float16)b0.w,
                           (_Float16)b1.x, (_Float16)b1.y, (_Float16)b1.z, (_Float16)b1.w};
      acc = __builtin_amdgcn_mfma_f32_16x16x32_f16(af, bf, acc, 0, 0, 0);
    }
    unsigned short tmp[4];
#pragma unroll
    for (int reg = 0; reg < 4; ++reg) tmp[reg] = f2h(acc[reg]);
    // fragment-order store: value (feature r, node m) -> gT2[head][js][c8][ss][kh*32+n32][e]
    const int r  = n0 + n16;          // feature row, head = r>>5, n32 = r&31
    const int m  = m0 + quad * 4;     // node base of this int2 (4 consecutive m)
    const int head_ = r >> 5, n32_ = r & 31;
    const int js_ = m >> 10, c8_ = (m >> 7) & 7, ss_ = (m >> 4) & 7;
    const int kh_ = (m >> 3) & 1, e_ = m & 7;  // e_ in {0,4}
    unsigned short* dst = gT2 + ((size_t)(head_ * 4 + js_) * 64 + (c8_ * 8 + ss_)) * 512
                              + (kh_ * 32 + n32_) * 8 + e_;
    *(int2*)dst = *(int2*)tmp;
  } else {
    // ---- bitmask: wave-contiguous loads. Lane l reads int4 (4 adj ints) at
    // lane-consecutive addresses (1 KB/instr, fully coalesced), packs a nibble,
    // 3-round shfl_xor OR-butterfly assembles the 32-bit word in groups of 8.
    const int lane = t & 63;
    const int wv   = t >> 6;
    const int row  = (b - 1280) * 2 + (wv >> 1);
    const int half = wv & 1;  // each wave covers 2048 ints = 8 KB
    const int4* src4 = (const int4*)(adj + (size_t)row * N) + half * 512 + lane;
    const int shamt = (lane & 7) * 4;
    unsigned int* dstw = bits + (size_t)row * (N / 32) + half * 64 + (lane >> 3);
#pragma unroll
    for (int it = 0; it < 8; ++it) {
      const int4 v4 = src4[it * 64];
      unsigned int v = ((unsigned)v4.x | ((unsigned)v4.y << 1) |
                        ((unsigned)v4.z << 2) | ((unsigned)v4.w << 3)) << shamt;
      v |= (unsigned)__shfl_xor((int)v, 1);
      v |= (unsigned)__shfl_xor((int)v, 2);
      v |= (unsigned)__shfl_xor((int)v, 4);
      if ((lane & 7) == 0) dstw[it * 8] = v;
    }
  }
}

// ================= K_AGG: 64i-tile 32x32 fp16-MFMA flash aggregation =================
// block = 64 i x head-pair x 1/4 j (1024 j); waves: (hd = wv>>1, isub = wv&1).
// BARRIER-FREE main loop: B-fragments come straight from L2-resident gT2 in
// fragment order (one coalesced b128 per lane), double-buffered one chunk deep
// in registers. Only LDS left is the 8 KB B/D broadcast slab (staged once).
constexpr int TI = 64;
constexpr int NSPLIT = 4;

__global__ __launch_bounds__(256, 4) void k_agg(
    const unsigned short* __restrict__ gT2,
    const unsigned int* __restrict__ RT2,
    const unsigned short* __restrict__ BT, const unsigned short* __restrict__ DT,
    const unsigned int* __restrict__ bits,
    float* __restrict__ parts, float* __restrict__ lparts) {
  __shared__ __align__(16) uint4 sBD[2][2][128];         // [B/D][head][1024 fp16]

  const int t    = threadIdx.x;
  const int lane = t & 63;
  const int wv   = t >> 6;
  const int isub = wv & 1;
  const int hd   = wv >> 1;
  const int b    = blockIdx.x;
  const int hp   = b & 3;
  const int js   = (b >> 2) & (NSPLIT - 1);
  const int i0   = (b >> 4) * TI;
  const int head = hp * 2 + hd;

  const int n32 = lane & 31;
  const int kh  = lane >> 5;

  const int myi = i0 + isub * 32 + n32;
  const unsigned int Ri2u = RT2[(size_t)myi * NH + head];
  h2 Ri2; __builtin_memcpy(&Ri2, &Ri2u, 4);
  const uint4* bp4 = (const uint4*)(bits + (size_t)myi * (N / 32) + js * 32);

  // per-(head,js) fragment block: [c8*8+ss][lane][8 shorts]
  const unsigned short* gfrag =
      gT2 + (size_t)(head * NSPLIT + js) * 32768 + (size_t)lane * 8;

  frag_c16 acc = {0.f, 0.f, 0.f, 0.f, 0.f, 0.f, 0.f, 0.f,
                  0.f, 0.f, 0.f, 0.f, 0.f, 0.f, 0.f, 0.f};
  frag_c16 accl = {0.f, 0.f, 0.f, 0.f, 0.f, 0.f, 0.f, 0.f,
                   0.f, 0.f, 0.f, 0.f, 0.f, 0.f, 0.f, 0.f};
  frag_f16 fone;
#pragma unroll
  for (int u = 0; u < 8; ++u) fone[u] = (_Float16)1.0f;

  {  // stage B/D slab once (2 heads x 1024 fp16 x 2 planes = 8 KB)
    const int hsel = t >> 7, idx = t & 127;
    sBD[0][hsel][idx] =
        ((const uint4*)(BT + (size_t)(hp * 2 + hsel) * N + js * 1024))[idx];
    sBD[1][hsel][idx] =
        ((const uint4*)(DT + (size_t)(hp * 2 + hsel) * N + js * 1024))[idx];
  }
  __syncthreads();

  // chunk-0 fragment preload (registers) + bits word
  int4 bva[8];
#pragma unroll
  for (int ss = 0; ss < 8; ++ss)
    bva[ss] = *(const int4*)(gfrag + (size_t)ss * 512);
  uint4 bw = bp4[0];

  for (int c8 = 0; c8 < 8; ++c8) {
    int4 nba[8];
    uint4 bwn = bw;
    if (c8 < 7) {  // depth-1 register prefetch of next chunk (no barriers anywhere)
      bwn = bp4[c8 + 1];
#pragma unroll
      for (int ss = 0; ss < 8; ++ss)
        nba[ss] = *(const int4*)(gfrag + (size_t)((c8 + 1) * 8 + ss) * 512);
    }
    const unsigned int bwa[4] = {bw.x, bw.y, bw.z, bw.w};
#pragma unroll
    for (int half = 0; half < 2; ++half) {
      // batch-hoist this half's B/D broadcast reads (8 x ds_read_b128)
      uint4 Bva[4], Dva[4];
#pragma unroll
      for (int q = 0; q < 4; ++q) {
        const int ss = half * 4 + q;
        Bva[q] = sBD[0][hd][c8 * 16 + ss * 2 + kh];
        Dva[q] = sBD[1][hd][c8 * 16 + ss * 2 + kh];
      }
#pragma unroll
      for (int q = 0; q < 4; ++q) {
        const int ss = half * 4 + q;
        const unsigned int mb = (bwa[ss >> 1] >> (((ss & 1) << 4) + (kh << 3))) & 0xFFu;
        const unsigned int bu[4] = {Bva[q].x, Bva[q].y, Bva[q].z, Bva[q].w};
        const unsigned int du[4] = {Dva[q].x, Dva[q].y, Dva[q].z, Dva[q].w};
        unsigned int packed[4];
#pragma unroll
        for (int p = 0; p < 4; ++p) {
          h2 hB, hD;
          __builtin_memcpy(&hB, &bu[p], 4);
          __builtin_memcpy(&hD, &du[p], 4);
          const h2 wm = __builtin_elementwise_max(hB, Ri2 * hD);  // pk_mul + pk_max
          unsigned int wp; __builtin_memcpy(&wp, &wm, 4);
          const unsigned int d  = (mb >> (2 * p)) & 3u;
          const unsigned int sp = ((d | (d << 15)) & 0x10001u) * 0xFFFFu;
          wp &= sp;
          packed[p] = wp;
        }
        frag_f16 af; __builtin_memcpy(&af, packed, 16);
        frag_f16 bf; __builtin_memcpy(&bf, &bva[ss], 16);

        acc  = __builtin_amdgcn_mfma_f32_32x32x16_f16(af, bf, acc, 0, 0, 0);
        accl = __builtin_amdgcn_mfma_f32_32x32x16_f16(af, fone, accl, 0, 0, 0);
      }
    }
    if (c8 < 7) {
#pragma unroll
      for (int ss = 0; ss < 8; ++ss) bva[ss] = nba[ss];
      bw = bwn;
    }
  }

  // ---- epilogue: non-atomic per-js partial stores (wave owns its rows) ----
  float* op = parts + (size_t)js * N * F;
#pragma unroll
  for (int reg = 0; reg < 16; ++reg) {
    const int row = (reg & 3) + 8 * (reg >> 2) + 4 * kh;
    op[(size_t)(i0 + isub * 32 + row) * F + head * HID + n32] = acc[reg];
  }
  if (n32 == 0) {  // accl cols are identical; lane n32==0 stores l for its 8 rows
    float* lp = lparts + (size_t)js * N * NH;
#pragma unroll
    for (int reg = 0; reg < 16; ++reg) {
      const int row = (reg & 3) + 8 * (reg >> 2) + 4 * kh;
      lp[(size_t)(i0 + isub * 32 + row) * NH + head] = accl[reg];
    }
  }
}

// ================= K_NORM: sum partials + normalize =================
__global__ __launch_bounds__(256) void k_norm(const float* __restrict__ parts,
                                              const float* __restrict__ lparts,
                                              float* __restrict__ out) {
  const int idx = blockIdx.x * 256 + threadIdx.x;  // float4 index over N*F/4
  const int i = idx >> 6, fq = idx & 63;
  const int hh = fq >> 3;
  float l = 0.f;
  float4 v = make_float4(0.f, 0.f, 0.f, 0.f);
#pragma unroll
  for (int js = 0; js < NSPLIT; ++js) {
    l += lparts[(size_t)js * N * NH + (size_t)i * NH + hh];
    const float4 p = *(const float4*)(parts + (size_t)js * N * F + (size_t)idx * 4);
    v.x += p.x; v.y += p.y; v.z += p.z; v.w += p.w;
  }
  const float inv = 1.f / l;
  v.x *= inv; v.y *= inv; v.z *= inv; v.w *= inv;
  *(float4*)(out + (size_t)idx * 4) = v;
}

extern "C" void kernel_launch(void* const* d_in, const int* in_sizes, int n_in,
                              void* d_out, int out_size, void* d_ws, size_t ws_size,
                              hipStream_t stream) {
  const float* h   = (const float*)d_in[0];
  const float* W   = (const float*)d_in[1];
  const float* a   = (const float*)d_in[2];
  const int*   adj = (const int*)d_in[3];
  float* out = (float*)d_out;

  // workspace (~21 MB)
  char* ws = (char*)d_ws;
  unsigned short* gT2 = (unsigned short*)ws; ws += (size_t)N * F * 2;        // 2 MB
  unsigned int* bits = (unsigned int*)ws;    ws += (size_t)N * (N / 32) * 4; // 2 MB
  unsigned int* RT2 = (unsigned int*)ws;     ws += (size_t)N * NH * 4;
  unsigned short* BT = (unsigned short*)ws;  ws += (size_t)N * NH * 2;
  unsigned short* DT = (unsigned short*)ws;  ws += (size_t)N * NH * 2;
  float* U    = (float*)ws;                  ws += 16 * F * 4;
  float* parts  = (float*)ws;                ws += (size_t)NSPLIT * N * F * 4;  // 16 MB
  float* lparts = (float*)ws;                ws += (size_t)NSPLIT * N * NH * 4; // 512 KB

  k_u<<<dim3(16), dim3(256), 0, stream>>>(W, a, U);
  k_front<<<dim3(3328), dim3(256), 0, stream>>>(h, W, U, adj, RT2, BT, DT, gT2, bits);
  k_agg<<<dim3((N / TI) * 4 * NSPLIT), dim3(256), 0, stream>>>(
      gT2, RT2, BT, DT, bits, parts, lparts);
  k_norm<<<dim3(N * F / 4 / 256), dim3(256), 0, stream>>>(parts, lparts, out);
}

// Round 9
// 150.413 us; speedup vs baseline: 1.1949x; 1.0112x over previous
//
#include <hip/hip_runtime.h>
#include <math.h>

constexpr int N   = 4096;   // nodes
constexpr int F   = 256;    // IN_FEAT (= NH*HID)
constexpr int NH  = 8;      // heads
constexpr int HID = 32;     // hidden per head
constexpr float SLOPE = 0.2f;

using h2       = __attribute__((ext_vector_type(2))) _Float16;
using frag_f16 = __attribute__((ext_vector_type(8))) _Float16;  // 4 VGPRs
using frag_cd  = __attribute__((ext_vector_type(4))) float;
using frag_c16 = __attribute__((ext_vector_type(16))) float;

__device__ inline unsigned short f2h(float x) {
  _Float16 v = (_Float16)x;
  unsigned short u; __builtin_memcpy(&u, &v, 2); return u;
}

// ================= K_U: U[c][k] = sum_f W[head*32+f][k] * a[side*32+f] =================
__global__ __launch_bounds__(256) void k_u(const float* __restrict__ W,
                                           const float* __restrict__ a,
                                           float* __restrict__ U) {
  const int c = blockIdx.x, k = threadIdx.x;
  const int head = c & 7, side = c >> 3;
  float acc = 0.f;
#pragma unroll
  for (int f = 0; f < 32; ++f)
    acc += W[(size_t)(head * 32 + f) * F + k] * a[side * 32 + f];
  U[c * F + k] = acc;
}

// ================= K_FRONT: everything before aggregation (ZERO LDS) =================
// [0,256):    s = h@U (U from global, L1-hot) -> RT2, BT, DT
// [256,512):  gT2 = (h @ W^T)^T fp16 via MFMA. One wave = 1 mt x 4 nt tiles:
//             A-fragments (h rows, L3) loaded ONCE per ks and reused across the
//             4 B tiles -> h re-read traffic 64->16 MB; 4 independent acc chains.
//             Stored in MFMA-FRAGMENT ORDER: gT2[head][js][c8][ss][kh*32+n32][8].
// [512,2560): adjacency bitmask: wave-contiguous int4 loads + shfl_xor packing
__global__ __launch_bounds__(256) void k_front(const float* __restrict__ h,
                                               const float* __restrict__ W,
                                               const float* __restrict__ U,
                                               const int* __restrict__ adj,
                                               unsigned int* __restrict__ RT2,
                                               unsigned short* __restrict__ BT,
                                               unsigned short* __restrict__ DT,
                                               unsigned short* __restrict__ gT2,
                                               unsigned int* __restrict__ bits) {
  const int b = blockIdx.x, t = threadIdx.x;
  if (b < 256) {
    // ---- s-part: thread (r,c); h-row reads broadcast across the 16 c-threads ----
    const int i0 = b * 16;
    const int r = t >> 4, c = t & 15;
    const float4* hp = (const float4*)(h + (size_t)(i0 + r) * F);
    const float4* up = (const float4*)(U + (size_t)c * F);
    float acc = 0.f;
#pragma unroll
    for (int k4 = 0; k4 < 64; ++k4) {
      const float4 hv = hp[k4];
      const float4 uv = up[k4];
      acc += hv.x * uv.x + hv.y * uv.y + hv.z * uv.z + hv.w * uv.w;
    }
    const int n = i0 + r;
    if (c < 8) {
      const unsigned int r16 = f2h(__expf(-0.8f * acc));
      RT2[(size_t)n * NH + c] = (r16 << 16) | r16;
    } else {
      const int hd = c - 8;
      BT[(size_t)hd * N + n] = f2h(__expf(acc));
      DT[(size_t)hd * N + n] = f2h(__expf(SLOPE * acc));
    }
  } else if (b < 512) {
    // ---- gT2 GEMM: one wave per 16x64 strip (1 mt x 4 nt), A reused 4x ----
    const int lane = t & 63;
    const int tile = (b - 256) * 4 + (t >> 6);   // 0..1023
    const int mt = tile >> 2, nt4 = tile & 3;
    const int m0 = mt * 16, n0 = nt4 * 64;
    const int n16 = lane & 15, quad = lane >> 4;
    frag_cd acc[4];
#pragma unroll
    for (int j = 0; j < 4; ++j) acc[j] = frag_cd{0.f, 0.f, 0.f, 0.f};
    const float* ap = h + (size_t)(m0 + n16) * F + quad * 8;
    const float* bp = W + (size_t)(n0 + n16) * F + quad * 8;
#pragma unroll
    for (int ks = 0; ks < F / 32; ++ks) {
      const float4 a0 = *(const float4*)(ap + ks * 32);
      const float4 a1 = *(const float4*)(ap + ks * 32 + 4);
      const frag_f16 af = {(_Float16)a0.x, (_Float16)a0.y, (_Float16)a0.z, (_Float16)a0.w,
                           (_Float16)a1.x, (_Float16)a1.y, (_Float16)a1.z, (_Float16)a1.w};
#pragma unroll
      for (int j = 0; j < 4; ++j) {
        const float4 b0 = *(const float4*)(bp + (size_t)j * 16 * F + ks * 32);
        const float4 b1 = *(const float4*)(bp + (size_t)j * 16 * F + ks * 32 + 4);
        const frag_f16 bf = {(_Float16)b0.x, (_Float16)b0.y, (_Float16)b0.z, (_Float16)b0.w,
                             (_Float16)b1.x, (_Float16)b1.y, (_Float16)b1.z, (_Float16)b1.w};
        acc[j] = __builtin_amdgcn_mfma_f32_16x16x32_f16(af, bf, acc[j], 0, 0, 0);
      }
    }
    // fragment-order stores: (feature r, node m) -> gT2[head][js][c8][ss][kh*32+n32][e]
    const int m  = m0 + quad * 4;
    const int js_ = m >> 10, c8_ = (m >> 7) & 7, ss_ = (m >> 4) & 7;
    const int kh_ = (m >> 3) & 1, e_ = m & 7;  // e_ in {0,4}
#pragma unroll
    for (int j = 0; j < 4; ++j) {
      unsigned short tmp[4];
#pragma unroll
      for (int reg = 0; reg < 4; ++reg) tmp[reg] = f2h(acc[j][reg]);
      const int r = n0 + j * 16 + n16;         // feature row
      const int head_ = r >> 5, n32_ = r & 31;
      unsigned short* dst = gT2 + ((size_t)(head_ * 4 + js_) * 64 + (c8_ * 8 + ss_)) * 512
                                + (kh_ * 32 + n32_) * 8 + e_;
      *(int2*)dst = *(int2*)tmp;
    }
  } else {
    // ---- bitmask: wave-contiguous loads. Lane l reads int4 (4 adj ints) at
    // lane-consecutive addresses (1 KB/instr, fully coalesced), packs a nibble,
    // 3-round shfl_xor OR-butterfly assembles the 32-bit word in groups of 8.
    const int lane = t & 63;
    const int wv   = t >> 6;
    const int row  = (b - 512) * 2 + (wv >> 1);
    const int half = wv & 1;  // each wave covers 2048 ints = 8 KB
    const int4* src4 = (const int4*)(adj + (size_t)row * N) + half * 512 + lane;
    const int shamt = (lane & 7) * 4;
    unsigned int* dstw = bits + (size_t)row * (N / 32) + half * 64 + (lane >> 3);
#pragma unroll
    for (int it = 0; it < 8; ++it) {
      const int4 v4 = src4[it * 64];
      unsigned int v = ((unsigned)v4.x | ((unsigned)v4.y << 1) |
                        ((unsigned)v4.z << 2) | ((unsigned)v4.w << 3)) << shamt;
      v |= (unsigned)__shfl_xor((int)v, 1);
      v |= (unsigned)__shfl_xor((int)v, 2);
      v |= (unsigned)__shfl_xor((int)v, 4);
      if ((lane & 7) == 0) dstw[it * 8] = v;
    }
  }
}

// ================= K_AGG: 64i-tile 32x32 fp16-MFMA flash aggregation =================
// block = 64 i x head-pair x 1/4 j (1024 j); waves: (hd = wv>>1, isub = wv&1).
// BARRIER-FREE main loop: B-fragments come straight from L2-resident gT2 in
// fragment order (one coalesced b128 per lane), double-buffered one chunk deep
// in registers. Only LDS left is the 8 KB B/D broadcast slab (staged once).
constexpr int TI = 64;
constexpr int NSPLIT = 4;

__global__ __launch_bounds__(256, 4) void k_agg(
    const unsigned short* __restrict__ gT2,
    const unsigned int* __restrict__ RT2,
    const unsigned short* __restrict__ BT, const unsigned short* __restrict__ DT,
    const unsigned int* __restrict__ bits,
    float* __restrict__ parts, float* __restrict__ lparts) {
  __shared__ __align__(16) uint4 sBD[2][2][128];         // [B/D][head][1024 fp16]

  const int t    = threadIdx.x;
  const int lane = t & 63;
  const int wv   = t >> 6;
  const int isub = wv & 1;
  const int hd   = wv >> 1;
  const int b    = blockIdx.x;
  const int hp   = b & 3;
  const int js   = (b >> 2) & (NSPLIT - 1);
  const int i0   = (b >> 4) * TI;
  const int head = hp * 2 + hd;

  const int n32 = lane & 31;
  const int kh  = lane >> 5;

  const int myi = i0 + isub * 32 + n32;
  const unsigned int Ri2u = RT2[(size_t)myi * NH + head];
  h2 Ri2; __builtin_memcpy(&Ri2, &Ri2u, 4);
  const uint4* bp4 = (const uint4*)(bits + (size_t)myi * (N / 32) + js * 32);

  // per-(head,js) fragment block: [c8*8+ss][lane][8 shorts]
  const unsigned short* gfrag =
      gT2 + (size_t)(head * NSPLIT + js) * 32768 + (size_t)lane * 8;

  frag_c16 acc = {0.f, 0.f, 0.f, 0.f, 0.f, 0.f, 0.f, 0.f,
                  0.f, 0.f, 0.f, 0.f, 0.f, 0.f, 0.f, 0.f};
  frag_c16 accl = {0.f, 0.f, 0.f, 0.f, 0.f, 0.f, 0.f, 0.f,
                   0.f, 0.f, 0.f, 0.f, 0.f, 0.f, 0.f, 0.f};
  frag_f16 fone;
#pragma unroll
  for (int u = 0; u < 8; ++u) fone[u] = (_Float16)1.0f;

  {  // stage B/D slab once (2 heads x 1024 fp16 x 2 planes = 8 KB)
    const int hsel = t >> 7, idx = t & 127;
    sBD[0][hsel][idx] =
        ((const uint4*)(BT + (size_t)(hp * 2 + hsel) * N + js * 1024))[idx];
    sBD[1][hsel][idx] =
        ((const uint4*)(DT + (size_t)(hp * 2 + hsel) * N + js * 1024))[idx];
  }
  __syncthreads();

  // chunk-0 fragment preload (registers) + bits word
  int4 bva[8];
#pragma unroll
  for (int ss = 0; ss < 8; ++ss)
    bva[ss] = *(const int4*)(gfrag + (size_t)ss * 512);
  uint4 bw = bp4[0];

  for (int c8 = 0; c8 < 8; ++c8) {
    int4 nba[8];
    uint4 bwn = bw;
    if (c8 < 7) {  // depth-1 register prefetch of next chunk (no barriers anywhere)
      bwn = bp4[c8 + 1];
#pragma unroll
      for (int ss = 0; ss < 8; ++ss)
        nba[ss] = *(const int4*)(gfrag + (size_t)((c8 + 1) * 8 + ss) * 512);
    }
    const unsigned int bwa[4] = {bw.x, bw.y, bw.z, bw.w};
#pragma unroll
    for (int half = 0; half < 2; ++half) {
      // batch-hoist this half's B/D broadcast reads (8 x ds_read_b128)
      uint4 Bva[4], Dva[4];
#pragma unroll
      for (int q = 0; q < 4; ++q) {
        const int ss = half * 4 + q;
        Bva[q] = sBD[0][hd][c8 * 16 + ss * 2 + kh];
        Dva[q] = sBD[1][hd][c8 * 16 + ss * 2 + kh];
      }
#pragma unroll
      for (int q = 0; q < 4; ++q) {
        const int ss = half * 4 + q;
        const unsigned int mb = (bwa[ss >> 1] >> (((ss & 1) << 4) + (kh << 3))) & 0xFFu;
        const unsigned int bu[4] = {Bva[q].x, Bva[q].y, Bva[q].z, Bva[q].w};
        const unsigned int du[4] = {Dva[q].x, Dva[q].y, Dva[q].z, Dva[q].w};
        unsigned int packed[4];
#pragma unroll
        for (int p = 0; p < 4; ++p) {
          h2 hB, hD;
          __builtin_memcpy(&hB, &bu[p], 4);
          __builtin_memcpy(&hD, &du[p], 4);
          const h2 wm = __builtin_elementwise_max(hB, Ri2 * hD);  // pk_mul + pk_max
          unsigned int wp; __builtin_memcpy(&wp, &wm, 4);
          const unsigned int d  = (mb >> (2 * p)) & 3u;
          const unsigned int sp = ((d | (d << 15)) & 0x10001u) * 0xFFFFu;
          wp &= sp;
          packed[p] = wp;
        }
        frag_f16 af; __builtin_memcpy(&af, packed, 16);
        frag_f16 bf; __builtin_memcpy(&bf, &bva[ss], 16);

        acc  = __builtin_amdgcn_mfma_f32_32x32x16_f16(af, bf, acc, 0, 0, 0);
        accl = __builtin_amdgcn_mfma_f32_32x32x16_f16(af, fone, accl, 0, 0, 0);
      }
    }
    if (c8 < 7) {
#pragma unroll
      for (int ss = 0; ss < 8; ++ss) bva[ss] = nba[ss];
      bw = bwn;
    }
  }

  // ---- epilogue: non-atomic per-js partial stores (wave owns its rows) ----
  float* op = parts + (size_t)js * N * F;
#pragma unroll
  for (int reg = 0; reg < 16; ++reg) {
    const int row = (reg & 3) + 8 * (reg >> 2) + 4 * kh;
    op[(size_t)(i0 + isub * 32 + row) * F + head * HID + n32] = acc[reg];
  }
  if (n32 == 0) {  // accl cols are identical; lane n32==0 stores l for its 8 rows
    float* lp = lparts + (size_t)js * N * NH;
#pragma unroll
    for (int reg = 0; reg < 16; ++reg) {
      const int row = (reg & 3) + 8 * (reg >> 2) + 4 * kh;
      lp[(size_t)(i0 + isub * 32 + row) * NH + head] = accl[reg];
    }
  }
}

// ================= K_NORM: sum partials + normalize =================
__global__ __launch_bounds__(256) void k_norm(const float* __restrict__ parts,
                                              const float* __restrict__ lparts,
                                              float* __restrict__ out) {
  const int idx = blockIdx.x * 256 + threadIdx.x;  // float4 index over N*F/4
  const int i = idx >> 6, fq = idx & 63;
  const int hh = fq >> 3;
  float l = 0.f;
  float4 v = make_float4(0.f, 0.f, 0.f, 0.f);
#pragma unroll
  for (int js = 0; js < NSPLIT; ++js) {
    l += lparts[(size_t)js * N * NH + (size_t)i * NH + hh];
    const float4 p = *(const float4*)(parts + (size_t)js * N * F + (size_t)idx * 4);
    v.x += p.x; v.y += p.y; v.z += p.z; v.w += p.w;
  }
  const float inv = 1.f / l;
  v.x *= inv; v.y *= inv; v.z *= inv; v.w *= inv;
  *(float4*)(out + (size_t)idx * 4) = v;
}

extern "C" void kernel_launch(void* const* d_in, const int* in_sizes, int n_in,
                              void* d_out, int out_size, void* d_ws, size_t ws_size,
                              hipStream_t stream) {
  const float* h   = (const float*)d_in[0];
  const float* W   = (const float*)d_in[1];
  const float* a   = (const float*)d_in[2];
  const int*   adj = (const int*)d_in[3];
  float* out = (float*)d_out;

  // workspace (~21 MB)
  char* ws = (char*)d_ws;
  unsigned short* gT2 = (unsigned short*)ws; ws += (size_t)N * F * 2;        // 2 MB
  unsigned int* bits = (unsigned int*)ws;    ws += (size_t)N * (N / 32) * 4; // 2 MB
  unsigned int* RT2 = (unsigned int*)ws;     ws += (size_t)N * NH * 4;
  unsigned short* BT = (unsigned short*)ws;  ws += (size_t)N * NH * 2;
  unsigned short* DT = (unsigned short*)ws;  ws += (size_t)N * NH * 2;
  float* U    = (float*)ws;                  ws += 16 * F * 4;
  float* parts  = (float*)ws;                ws += (size_t)NSPLIT * N * F * 4;  // 16 MB
  float* lparts = (float*)ws;                ws += (size_t)NSPLIT * N * NH * 4; // 512 KB

  k_u<<<dim3(16), dim3(256), 0, stream>>>(W, a, U);
  k_front<<<dim3(2560), dim3(256), 0, stream>>>(h, W, U, adj, RT2, BT, DT, gT2, bits);
  k_agg<<<dim3((N / TI) * 4 * NSPLIT), dim3(256), 0, stream>>>(
      gT2, RT2, BT, DT, bits, parts, lparts);
  k_norm<<<dim3(N * F / 4 / 256), dim3(256), 0, stream>>>(parts, lparts, out);
}

// Round 10
// 150.330 us; speedup vs baseline: 1.1955x; 1.0006x over previous
//
#include <hip/hip_runtime.h>
#include <math.h>

constexpr int N   = 4096;   // nodes
constexpr int F   = 256;    // IN_FEAT (= NH*HID)
constexpr int NH  = 8;      // heads
constexpr int HID = 32;     // hidden per head
constexpr float SLOPE = 0.2f;

using h2       = __attribute__((ext_vector_type(2))) _Float16;
using frag_f16 = __attribute__((ext_vector_type(8))) _Float16;  // 4 VGPRs
using frag_cd  = __attribute__((ext_vector_type(4))) float;
using frag_c16 = __attribute__((ext_vector_type(16))) float;

__device__ inline unsigned short f2h(float x) {
  _Float16 v = (_Float16)x;
  unsigned short u; __builtin_memcpy(&u, &v, 2); return u;
}

// ================= K_U: U[c][k] = sum_f W[head*32+f][k] * a[side*32+f] =================
__global__ __launch_bounds__(256) void k_u(const float* __restrict__ W,
                                           const float* __restrict__ a,
                                           float* __restrict__ U) {
  const int c = blockIdx.x, k = threadIdx.x;
  const int head = c & 7, side = c >> 3;
  float acc = 0.f;
#pragma unroll
  for (int f = 0; f < 32; ++f)
    acc += W[(size_t)(head * 32 + f) * F + k] * a[side * 32 + f];
  U[c * F + k] = acc;
}

// ================= K_FRONT: everything before aggregation (ZERO LDS) =================
// [0,256):    s = h@U (U from global, L1-hot) -> RT2, BT, DT
// [256,512):  gT2 = (h @ W^T)^T fp16 via MFMA, 1 mt x 4 nt per wave (A reused 4x),
//             stored in MFMA-FRAGMENT ORDER: gT2[head][js][c8][ss][kh*32+n32][8].
// [512,2560): adjacency bitmask via __ballot: one v_cmp per 64 ints, NO DS ops,
//             no serial cross-lane chains (replaces 3x ds_swizzle/iter).
__global__ __launch_bounds__(256) void k_front(const float* __restrict__ h,
                                               const float* __restrict__ W,
                                               const float* __restrict__ U,
                                               const int* __restrict__ adj,
                                               unsigned int* __restrict__ RT2,
                                               unsigned short* __restrict__ BT,
                                               unsigned short* __restrict__ DT,
                                               unsigned short* __restrict__ gT2,
                                               unsigned int* __restrict__ bits) {
  const int b = blockIdx.x, t = threadIdx.x;
  if (b < 256) {
    // ---- s-part: thread (r,c); h-row reads broadcast across the 16 c-threads ----
    const int i0 = b * 16;
    const int r = t >> 4, c = t & 15;
    const float4* hp = (const float4*)(h + (size_t)(i0 + r) * F);
    const float4* up = (const float4*)(U + (size_t)c * F);
    float acc = 0.f;
#pragma unroll
    for (int k4 = 0; k4 < 64; ++k4) {
      const float4 hv = hp[k4];
      const float4 uv = up[k4];
      acc += hv.x * uv.x + hv.y * uv.y + hv.z * uv.z + hv.w * uv.w;
    }
    const int n = i0 + r;
    if (c < 8) {
      const unsigned int r16 = f2h(__expf(-0.8f * acc));
      RT2[(size_t)n * NH + c] = (r16 << 16) | r16;
    } else {
      const int hd = c - 8;
      BT[(size_t)hd * N + n] = f2h(__expf(acc));
      DT[(size_t)hd * N + n] = f2h(__expf(SLOPE * acc));
    }
  } else if (b < 512) {
    // ---- gT2 GEMM: one wave per 16x64 strip (1 mt x 4 nt), A reused 4x ----
    const int lane = t & 63;
    const int tile = (b - 256) * 4 + (t >> 6);   // 0..1023
    const int mt = tile >> 2, nt4 = tile & 3;
    const int m0 = mt * 16, n0 = nt4 * 64;
    const int n16 = lane & 15, quad = lane >> 4;
    frag_cd acc[4];
#pragma unroll
    for (int j = 0; j < 4; ++j) acc[j] = frag_cd{0.f, 0.f, 0.f, 0.f};
    const float* ap = h + (size_t)(m0 + n16) * F + quad * 8;
    const float* bp = W + (size_t)(n0 + n16) * F + quad * 8;
#pragma unroll
    for (int ks = 0; ks < F / 32; ++ks) {
      const float4 a0 = *(const float4*)(ap + ks * 32);
      const float4 a1 = *(const float4*)(ap + ks * 32 + 4);
      const frag_f16 af = {(_Float16)a0.x, (_Float16)a0.y, (_Float16)a0.z, (_Float16)a0.w,
                           (_Float16)a1.x, (_Float16)a1.y, (_Float16)a1.z, (_Float16)a1.w};
#pragma unroll
      for (int j = 0; j < 4; ++j) {
        const float4 b0 = *(const float4*)(bp + (size_t)j * 16 * F + ks * 32);
        const float4 b1 = *(const float4*)(bp + (size_t)j * 16 * F + ks * 32 + 4);
        const frag_f16 bf = {(_Float16)b0.x, (_Float16)b0.y, (_Float16)b0.z, (_Float16)b0.w,
                             (_Float16)b1.x, (_Float16)b1.y, (_Float16)b1.z, (_Float16)b1.w};
        acc[j] = __builtin_amdgcn_mfma_f32_16x16x32_f16(af, bf, acc[j], 0, 0, 0);
      }
    }
    // fragment-order stores: (feature r, node m) -> gT2[head][js][c8][ss][kh*32+n32][e]
    const int m  = m0 + quad * 4;
    const int js_ = m >> 10, c8_ = (m >> 7) & 7, ss_ = (m >> 4) & 7;
    const int kh_ = (m >> 3) & 1, e_ = m & 7;  // e_ in {0,4}
#pragma unroll
    for (int j = 0; j < 4; ++j) {
      unsigned short tmp[4];
#pragma unroll
      for (int reg = 0; reg < 4; ++reg) tmp[reg] = f2h(acc[j][reg]);
      const int r = n0 + j * 16 + n16;         // feature row
      const int head_ = r >> 5, n32_ = r & 31;
      unsigned short* dst = gT2 + ((size_t)(head_ * 4 + js_) * 64 + (c8_ * 8 + ss_)) * 512
                                + (kh_ * 32 + n32_) * 8 + e_;
      *(int2*)dst = *(int2*)tmp;
    }
  } else {
    // ---- bitmask via ballot: lane l tests adj[base + q*64 + l]; one v_cmp
    // yields 64 bits (2 output words). 4 coalesced dword loads + 4 ballots per
    // 256 ints. Word w bit j = adj[row, w*32+j] (same layout as before).
    const int lane = t & 63;
    const int wv   = t >> 6;
    const int row  = (b - 512) * 2 + (wv >> 1);
    const int half = wv & 1;  // each wave covers 2048 ints = 8 KB
    const int* src = adj + (size_t)row * N + half * 2048 + lane;
    unsigned int* dstw = bits + (size_t)row * (N / 32) + half * 64;
#pragma unroll
    for (int it = 0; it < 8; ++it) {
      const int v0 = src[it * 256];
      const int v1 = src[it * 256 + 64];
      const int v2 = src[it * 256 + 128];
      const int v3 = src[it * 256 + 192];
      const unsigned long long m0 = __ballot(v0 & 1);
      const unsigned long long m1 = __ballot(v1 & 1);
      const unsigned long long m2 = __ballot(v2 & 1);
      const unsigned long long m3 = __ballot(v3 & 1);
      if (lane < 8) {
        const unsigned long long ms = (lane & 4) ? ((lane & 2) ? m3 : m2)
                                                 : ((lane & 2) ? m1 : m0);
        const unsigned int w = (unsigned int)(ms >> ((lane & 1) * 32));
        dstw[it * 8 + lane] = w;
      }
    }
  }
}

// ================= K_AGG: 64i-tile 32x32 fp16-MFMA flash aggregation =================
// block = 64 i x head-pair x 1/4 j (1024 j); waves: (hd = wv>>1, isub = wv&1).
// BARRIER-FREE main loop: B-fragments come straight from L2-resident gT2 in
// fragment order (one coalesced b128 per lane), double-buffered one chunk deep
// in registers. Only LDS left is the 8 KB B/D broadcast slab (staged once).
constexpr int TI = 64;
constexpr int NSPLIT = 4;

__global__ __launch_bounds__(256, 4) void k_agg(
    const unsigned short* __restrict__ gT2,
    const unsigned int* __restrict__ RT2,
    const unsigned short* __restrict__ BT, const unsigned short* __restrict__ DT,
    const unsigned int* __restrict__ bits,
    float* __restrict__ parts, float* __restrict__ lparts) {
  __shared__ __align__(16) uint4 sBD[2][2][128];         // [B/D][head][1024 fp16]

  const int t    = threadIdx.x;
  const int lane = t & 63;
  const int wv   = t >> 6;
  const int isub = wv & 1;
  const int hd   = wv >> 1;
  const int b    = blockIdx.x;
  const int hp   = b & 3;
  const int js   = (b >> 2) & (NSPLIT - 1);
  const int i0   = (b >> 4) * TI;
  const int head = hp * 2 + hd;

  const int n32 = lane & 31;
  const int kh  = lane >> 5;

  const int myi = i0 + isub * 32 + n32;
  const unsigned int Ri2u = RT2[(size_t)myi * NH + head];
  h2 Ri2; __builtin_memcpy(&Ri2, &Ri2u, 4);
  const uint4* bp4 = (const uint4*)(bits + (size_t)myi * (N / 32) + js * 32);

  // per-(head,js) fragment block: [c8*8+ss][lane][8 shorts]
  const unsigned short* gfrag =
      gT2 + (size_t)(head * NSPLIT + js) * 32768 + (size_t)lane * 8;

  frag_c16 acc = {0.f, 0.f, 0.f, 0.f, 0.f, 0.f, 0.f, 0.f,
                  0.f, 0.f, 0.f, 0.f, 0.f, 0.f, 0.f, 0.f};
  frag_c16 accl = {0.f, 0.f, 0.f, 0.f, 0.f, 0.f, 0.f, 0.f,
                   0.f, 0.f, 0.f, 0.f, 0.f, 0.f, 0.f, 0.f};
  frag_f16 fone;
#pragma unroll
  for (int u = 0; u < 8; ++u) fone[u] = (_Float16)1.0f;

  {  // stage B/D slab once (2 heads x 1024 fp16 x 2 planes = 8 KB)
    const int hsel = t >> 7, idx = t & 127;
    sBD[0][hsel][idx] =
        ((const uint4*)(BT + (size_t)(hp * 2 + hsel) * N + js * 1024))[idx];
    sBD[1][hsel][idx] =
        ((const uint4*)(DT + (size_t)(hp * 2 + hsel) * N + js * 1024))[idx];
  }
  __syncthreads();

  // chunk-0 fragment preload (registers) + bits word
  int4 bva[8];
#pragma unroll
  for (int ss = 0; ss < 8; ++ss)
    bva[ss] = *(const int4*)(gfrag + (size_t)ss * 512);
  uint4 bw = bp4[0];

  for (int c8 = 0; c8 < 8; ++c8) {
    int4 nba[8];
    uint4 bwn = bw;
    if (c8 < 7) {  // depth-1 register prefetch of next chunk (no barriers anywhere)
      bwn = bp4[c8 + 1];
#pragma unroll
      for (int ss = 0; ss < 8; ++ss)
        nba[ss] = *(const int4*)(gfrag + (size_t)((c8 + 1) * 8 + ss) * 512);
    }
    const unsigned int bwa[4] = {bw.x, bw.y, bw.z, bw.w};
#pragma unroll
    for (int half = 0; half < 2; ++half) {
      // batch-hoist this half's B/D broadcast reads (8 x ds_read_b128)
      uint4 Bva[4], Dva[4];
#pragma unroll
      for (int q = 0; q < 4; ++q) {
        const int ss = half * 4 + q;
        Bva[q] = sBD[0][hd][c8 * 16 + ss * 2 + kh];
        Dva[q] = sBD[1][hd][c8 * 16 + ss * 2 + kh];
      }
#pragma unroll
      for (int q = 0; q < 4; ++q) {
        const int ss = half * 4 + q;
        const unsigned int mb = (bwa[ss >> 1] >> (((ss & 1) << 4) + (kh << 3))) & 0xFFu;
        const unsigned int bu[4] = {Bva[q].x, Bva[q].y, Bva[q].z, Bva[q].w};
        const unsigned int du[4] = {Dva[q].x, Dva[q].y, Dva[q].z, Dva[q].w};
        unsigned int packed[4];
#pragma unroll
        for (int p = 0; p < 4; ++p) {
          h2 hB, hD;
          __builtin_memcpy(&hB, &bu[p], 4);
          __builtin_memcpy(&hD, &du[p], 4);
          const h2 wm = __builtin_elementwise_max(hB, Ri2 * hD);  // pk_mul + pk_max
          unsigned int wp; __builtin_memcpy(&wp, &wm, 4);
          const unsigned int d  = (mb >> (2 * p)) & 3u;
          const unsigned int sp = ((d | (d << 15)) & 0x10001u) * 0xFFFFu;
          wp &= sp;
          packed[p] = wp;
        }
        frag_f16 af; __builtin_memcpy(&af, packed, 16);
        frag_f16 bf; __builtin_memcpy(&bf, &bva[ss], 16);

        acc  = __builtin_amdgcn_mfma_f32_32x32x16_f16(af, bf, acc, 0, 0, 0);
        accl = __builtin_amdgcn_mfma_f32_32x32x16_f16(af, fone, accl, 0, 0, 0);
      }
    }
    if (c8 < 7) {
#pragma unroll
      for (int ss = 0; ss < 8; ++ss) bva[ss] = nba[ss];
      bw = bwn;
    }
  }

  // ---- epilogue: non-atomic per-js partial stores (wave owns its rows) ----
  float* op = parts + (size_t)js * N * F;
#pragma unroll
  for (int reg = 0; reg < 16; ++reg) {
    const int row = (reg & 3) + 8 * (reg >> 2) + 4 * kh;
    op[(size_t)(i0 + isub * 32 + row) * F + head * HID + n32] = acc[reg];
  }
  if (n32 == 0) {  // accl cols are identical; lane n32==0 stores l for its 8 rows
    float* lp = lparts + (size_t)js * N * NH;
#pragma unroll
    for (int reg = 0; reg < 16; ++reg) {
      const int row = (reg & 3) + 8 * (reg >> 2) + 4 * kh;
      lp[(size_t)(i0 + isub * 32 + row) * NH + head] = accl[reg];
    }
  }
}

// ================= K_NORM: sum partials + normalize =================
__global__ __launch_bounds__(256) void k_norm(const float* __restrict__ parts,
                                              const float* __restrict__ lparts,
                                              float* __restrict__ out) {
  const int idx = blockIdx.x * 256 + threadIdx.x;  // float4 index over N*F/4
  const int i = idx >> 6, fq = idx & 63;
  const int hh = fq >> 3;
  float l = 0.f;
  float4 v = make_float4(0.f, 0.f, 0.f, 0.f);
#pragma unroll
  for (int js = 0; js < NSPLIT; ++js) {
    l += lparts[(size_t)js * N * NH + (size_t)i * NH + hh];
    const float4 p = *(const float4*)(parts + (size_t)js * N * F + (size_t)idx * 4);
    v.x += p.x; v.y += p.y; v.z += p.z; v.w += p.w;
  }
  const float inv = 1.f / l;
  v.x *= inv; v.y *= inv; v.z *= inv; v.w *= inv;
  *(float4*)(out + (size_t)idx * 4) = v;
}

extern "C" void kernel_launch(void* const* d_in, const int* in_sizes, int n_in,
                              void* d_out, int out_size, void* d_ws, size_t ws_size,
                              hipStream_t stream) {
  const float* h   = (const float*)d_in[0];
  const float* W   = (const float*)d_in[1];
  const float* a   = (const float*)d_in[2];
  const int*   adj = (const int*)d_in[3];
  float* out = (float*)d_out;

  // workspace (~21 MB)
  char* ws = (char*)d_ws;
  unsigned short* gT2 = (unsigned short*)ws; ws += (size_t)N * F * 2;        // 2 MB
  unsigned int* bits = (unsigned int*)ws;    ws += (size_t)N * (N / 32) * 4; // 2 MB
  unsigned int* RT2 = (unsigned int*)ws;     ws += (size_t)N * NH * 4;
  unsigned short* BT = (unsigned short*)ws;  ws += (size_t)N * NH * 2;
  unsigned short* DT = (unsigned short*)ws;  ws += (size_t)N * NH * 2;
  float* U    = (float*)ws;                  ws += 16 * F * 4;
  float* parts  = (float*)ws;                ws += (size_t)NSPLIT * N * F * 4;  // 16 MB
  float* lparts = (float*)ws;                ws += (size_t)NSPLIT * N * NH * 4; // 512 KB

  k_u<<<dim3(16), dim3(256), 0, stream>>>(W, a, U);
  k_front<<<dim3(2560), dim3(256), 0, stream>>>(h, W, U, adj, RT2, BT, DT, gT2, bits);
  k_agg<<<dim3((N / TI) * 4 * NSPLIT), dim3(256), 0, stream>>>(
      gT2, RT2, BT, DT, bits, parts, lparts);
  k_norm<<<dim3(N * F / 4 / 256), dim3(256), 0, stream>>>(parts, lparts, out);
}